// Round 14
// baseline (20.278 us; speedup 1.0000x reference)
//
#include <hip/hip_runtime.h>

#define BLOCK 256
#define EPSF 1e-8f

// 16-byte vector load with only 4-byte alignment guarantee (rows are 44 B).
typedef float f4u __attribute__((ext_vector_type(4), aligned(4)));
// packed pair: component x = box iA, component y = box iB (VOP3P target)
typedef float pf2 __attribute__((ext_vector_type(2)));

struct Row9 { f4u b0, b1, b2, t0, t1, t2, w0, w1, w2; };

__device__ __forceinline__ Row9 load_row(const float* __restrict__ box,
                                         const float* __restrict__ tgt,
                                         const float* __restrict__ wgt,
                                         int row) {
    const size_t r = (size_t)row * 11;
    Row9 R;
    R.b0 = *(const f4u*)(box + r); R.b1 = *(const f4u*)(box + r + 4); R.b2 = *(const f4u*)(box + r + 7);
    R.t0 = *(const f4u*)(tgt + r); R.t1 = *(const f4u*)(tgt + r + 4); R.t2 = *(const f4u*)(tgt + r + 7);
    R.w0 = *(const f4u*)(wgt + r); R.w1 = *(const f4u*)(wgt + r + 4); R.w2 = *(const f4u*)(wgt + r + 7);
    return R;
}

__device__ __forceinline__ pf2 mk(float a, float b) { pf2 r; r.x = a; r.y = b; return r; }
__device__ __forceinline__ pf2 sp(float v) { pf2 r; r.x = v; r.y = v; return r; }
__device__ __forceinline__ pf2 pmin(pf2 a, pf2 b) { return __builtin_elementwise_min(a, b); }
__device__ __forceinline__ pf2 pmax(pf2 a, pf2 b) { return __builtin_elementwise_max(a, b); }
__device__ __forceinline__ pf2 pabs(pf2 a) { return __builtin_elementwise_abs(a); }

__device__ __forceinline__ float srcp1(float d) {
    float sd = (fabsf(d) > 1e-30f) ? d : copysignf(1e-30f, d);
    return __frcp_rn(sd);
}
__device__ __forceinline__ pf2 srcp(pf2 d) { pf2 r; r.x = srcp1(d.x); r.y = srcp1(d.y); return r; }
__device__ __forceinline__ pf2 pexp(pf2 d) { pf2 r; r.x = __expf(d.x); r.y = __expf(d.y); return r; }
__device__ __forceinline__ pf2 prsq(pf2 d) { pf2 r; r.x = rsqrtf(d.x); r.y = rsqrtf(d.y); return r; }
__device__ __forceinline__ pf2 prcp(pf2 d) { pf2 r; r.x = __frcp_rn(d.x); r.y = __frcp_rn(d.y); return r; }

// Packed clip_len: pure min/max/mul/sub -> v_pk_* candidates.
__device__ __forceinline__ pf2 clip_len2(pf2 px, pf2 py, pf2 rdx, pf2 rdy,
                                         pf2 hx, pf2 hy) {
    pf2 t1x = (-hx - px) * rdx, t2x = (hx - px) * rdx;
    pf2 t1y = (-hy - py) * rdy, t2y = (hy - py) * rdy;
    pf2 tmin = pmax(pmax(pmin(t1x, t2x), pmin(t1y, t2y)), sp(0.f));
    pf2 tmax = pmin(pmin(pmax(t1x, t2x), pmax(t1y, t2y)), sp(1.f));
    return pmax(tmax - tmin, sp(0.f));
}

#define PK(m) mk(A.m, B.m)

// Two boxes (A in .x, B in .y) computed with packed fp32 math (R9 algorithm).
__device__ __forceinline__ void pair_compute(const Row9& A, const Row9& B,
                                             pf2& l1out, pf2& gout)
{
    // ---- L1 loss: 11 packed abs-diff-FMAs ----
    pf2 lb;
    lb  = pabs(PK(b0.x) - PK(t0.x)) * PK(w0.x);
    lb += pabs(PK(b0.y) - PK(t0.y)) * PK(w0.y);
    lb += pabs(PK(b0.z) - PK(t0.z)) * PK(w0.z);
    lb += pabs(PK(b0.w) - PK(t0.w)) * PK(w0.w);
    lb += pabs(PK(b1.x) - PK(t1.x)) * PK(w1.x);
    lb += pabs(PK(b1.y) - PK(t1.y)) * PK(w1.y);
    lb += pabs(PK(b1.z) - PK(t1.z)) * PK(w1.z);
    lb += pabs(PK(b1.w) - PK(t1.w)) * PK(w1.w);
    lb += pabs(PK(b2.y) - PK(t2.y)) * PK(w2.y);
    lb += pabs(PK(b2.z) - PK(t2.z)) * PK(w2.z);
    lb += pabs(PK(b2.w) - PK(t2.w)) * PK(w2.w);
    l1out = lb;

    // ---- decode ----
    pf2 cx1 = PK(b0.x), cy1 = PK(b0.y), cx2 = PK(t0.x), cy2 = PK(t0.y);
    pf2 w1v = pexp(PK(b0.w)), l1v = pexp(PK(b1.x));
    pf2 w2v = pexp(PK(t0.w)), l2v = pexp(PK(t1.x));
    pf2 sy1 = PK(b1.z), cw1 = PK(b1.w), sy2 = PK(t1.z), cw2 = PK(t1.w);
    pf2 r1 = prsq(pmax(sy1 * sy1 + cw1 * cw1, sp(1e-30f)));
    pf2 s1 = sy1 * r1, c1 = cw1 * r1;
    pf2 r2 = prsq(pmax(sy2 * sy2 + cw2 * cw2, sp(1e-30f)));
    pf2 s2 = sy2 * r2, c2 = cw2 * r2;

    pf2 hx1 = 0.5f * w1v, hy1 = 0.5f * l1v;
    pf2 hx2 = 0.5f * w2v, hy2 = 0.5f * l2v;

    // ---- enclosing AABB (closed form) ----
    pf2 e1x = pabs(hx1 * c1) + pabs(hy1 * s1);
    pf2 e1y = pabs(hx1 * s1) + pabs(hy1 * c1);
    pf2 e2x = pabs(hx2 * c2) + pabs(hy2 * s2);
    pf2 e2y = pabs(hx2 * s2) + pabs(hy2 * c2);
    pf2 enc = (pmax(cx1 + e1x, cx2 + e2x) - pmin(cx1 - e1x, cx2 - e2x))
            * (pmax(cy1 + e1y, cy2 + e2y) - pmin(cy1 - e1y, cy2 - e2y));

    // ---- rect1 pose in rect2 frame ----
    pf2 dxw = cx1 - cx2, dyw = cy1 - cy2;
    pf2 txl =  c2 * dxw + s2 * dyw;
    pf2 tyl = -s2 * dxw + c2 * dyw;
    pf2 cr = c1 * c2 + s1 * s2;
    pf2 sr = s1 * c2 - c1 * s2;

    pf2 ax = hx1 * cr, ay = hx1 * sr;
    pf2 bx = hy1 * sr, by = hy1 * cr;
    pf2 q0x = txl - ax + bx, q0y = tyl - ay - by;
    pf2 q1x = txl + ax + bx, q1y = tyl + ay - by;
    pf2 q2x = txl + ax - bx, q2y = tyl + ay + by;
    pf2 q3x = txl - ax - bx, q3y = tyl - ay + by;

    // ---- Green's theorem intersection ----
    pf2 inter2 = sp(0.f);
    {
        pf2 d01x = 2.f * ax, d01y = 2.f * ay;
        pf2 d12x = -2.f * bx, d12y = 2.f * by;
        pf2 r01x = srcp(d01x), r01y = srcp(d01y);
        pf2 r12x = srcp(d12x), r12y = srcp(d12y);
        pf2 L0 = clip_len2(q0x, q0y, r01x, r01y, hx2, hy2);
        inter2 += L0 * (q0x * d01y - q0y * d01x);
        pf2 L1 = clip_len2(q1x, q1y, r12x, r12y, hx2, hy2);
        inter2 += L1 * (q1x * d12y - q1y * d12x);
        pf2 L2 = clip_len2(q2x, q2y, -r01x, -r01y, hx2, hy2);
        inter2 += L2 * (q2y * d01x - q2x * d01y);
        pf2 L3 = clip_len2(q3x, q3y, -r12x, -r12y, hx2, hy2);
        inter2 += L3 * (q3y * d12x - q3x * d12y);
    }
    {
        pf2 zx = -hx2 - txl, zy = -hy2 - tyl;
        pf2 u0x =  cr * zx + sr * zy;
        pf2 u0y = -sr * zx + cr * zy;
        pf2 E0x =  2.f * hx2 * cr, E0y = -2.f * hx2 * sr;
        pf2 E1x =  2.f * hy2 * sr, E1y =  2.f * hy2 * cr;
        pf2 u1x = u0x + E0x, u1y = u0y + E0y;
        pf2 u2x = u1x + E1x, u2y = u1y + E1y;
        pf2 u3x = u0x + E1x, u3y = u0y + E1y;
        pf2 re0x = srcp(E0x), re0y = srcp(E0y);
        pf2 re1x = srcp(E1x), re1y = srcp(E1y);
        pf2 tsum = clip_len2(u0x, u0y, re0x, re0y, hx1, hy1);
        tsum += clip_len2(u1x, u1y, re1x, re1y, hx1, hy1);
        tsum += clip_len2(u2x, u2y, -re0x, -re0y, hx1, hy1);
        tsum += clip_len2(u3x, u3y, -re1x, -re1y, hx1, hy1);
        inter2 += 2.f * (hx2 * hy2) * tsum;
    }

    pf2 inter = 0.5f * pabs(inter2);
    pf2 areaU = w1v * l1v + w2v * l2v - inter;
    pf2 iou = inter * prcp(areaU + sp(EPSF));
    pf2 giou = iou - (enc - areaU) * prcp(enc + sp(EPSF));
    gout = sp(1.f) - giou;
}

// Two boxes per thread in packed fp32 lanes; loads issued up front.
__global__ __launch_bounds__(BLOCK) void box_loss_main(
    const float* __restrict__ box, const float* __restrict__ tgt,
    const float* __restrict__ wgt, int n, int T, float* __restrict__ partials)
{
    __shared__ float red[8];

    const int tid = threadIdx.x;
    const int iA = blockIdx.x * BLOCK + tid;
    const int iB = iA + T;
    const bool hasA = iA < n, hasB = iB < n;

    Row9 A = load_row(box, tgt, wgt, hasA ? iA : 0);
    Row9 B = load_row(box, tgt, wgt, hasB ? iB : 0);

    pf2 l1, g;
    pair_compute(A, B, l1, g);

    float sumL1 = (hasA ? l1.x : 0.f) + (hasB ? l1.y : 0.f);
    float sumG  = (hasA ? g.x  : 0.f) + (hasB ? g.y  : 0.f);

    // ---- block reduction (wave=64) ----
#pragma unroll
    for (int off = 32; off > 0; off >>= 1) {
        sumL1 += __shfl_down(sumL1, off);
        sumG  += __shfl_down(sumG, off);
    }
    const int wave = tid >> 6, lane = tid & 63;
    if (lane == 0) { red[wave] = sumL1; red[4 + wave] = sumG; }
    __syncthreads();
    if (tid == 0) {
        partials[2 * (size_t)blockIdx.x]     = red[0] + red[1] + red[2] + red[3];
        partials[2 * (size_t)blockIdx.x + 1] = red[4] + red[5] + red[6] + red[7];
    }
}

// Deterministic final reduction of per-block partials + 1/af scaling.
__global__ __launch_bounds__(256) void box_loss_final(
    const float* __restrict__ partials, int nblk,
    const int* __restrict__ avg_factor, float* __restrict__ out)
{
    __shared__ float red[8];
    float a = 0.f, g = 0.f;
    for (int i = threadIdx.x; i < nblk; i += 256) {
        a += partials[2 * (size_t)i];
        g += partials[2 * (size_t)i + 1];
    }
#pragma unroll
    for (int off = 32; off > 0; off >>= 1) {
        a += __shfl_down(a, off);
        g += __shfl_down(g, off);
    }
    const int wave = threadIdx.x >> 6, lane = threadIdx.x & 63;
    if (lane == 0) { red[wave] = a; red[4 + wave] = g; }
    __syncthreads();
    if (threadIdx.x == 0) {
        float af = (float)(*avg_factor);
        if (af < 1.f) af = 1.f;
        out[0] = (red[0] + red[1] + red[2] + red[3]) / af;
        out[1] = (red[4] + red[5] + red[6] + red[7]) / af;
    }
}

extern "C" void kernel_launch(void* const* d_in, const int* in_sizes, int n_in,
                              void* d_out, int out_size, void* d_ws, size_t ws_size,
                              hipStream_t stream) {
    const float* box = (const float*)d_in[0];
    const float* tgt = (const float*)d_in[1];
    const float* wgt = (const float*)d_in[2];
    const int*   af  = (const int*)d_in[3];
    float* out = (float*)d_out;
    float* partials = (float*)d_ws;

    int n = in_sizes[0] / 11;
    int nblk = (n + BLOCK * 2 - 1) / (BLOCK * 2);   // 1024 for N=524288
    if (nblk < 1) nblk = 1;
    int T = nblk * BLOCK;   // thread handles iA = i and iB = i + T

    hipLaunchKernelGGL(box_loss_main, dim3(nblk), dim3(BLOCK), 0, stream,
                       box, tgt, wgt, n, T, partials);
    hipLaunchKernelGGL(box_loss_final, dim3(1), dim3(256), 0, stream,
                       partials, nblk, af, out);
}